// Round 1
// baseline (830.001 us; speedup 1.0000x reference)
//
#include <hip/hip_runtime.h>
#include <hip/hip_bf16.h>

// DILATE loss: 0.5 * mean_k softDTW_gamma(D_k) + 0.5 * mean_k (sum_ij E_k[i,j]*(i-j)^2) / N^2
// D_k[i,j] = (targets[k,i] - outputs[k,j])^2, gamma = 0.01, BIG = 1e10 boundary sentinel.
// E = dR[N-1,N-1]/dD, computed by the reverse soft-DTW recursion.

#define N_SEQ 512
#define NDIAG (2 * N_SEQ - 1)
#define GAMMA 0.01f
#define INVG 100.0f
#define BIG 1e10f
#define ALPHA 0.5f

// slab of R values for one sample, diagonal-major: [NDIAG][N_SEQ] floats
#define SLAB ((size_t)NDIAG * N_SEQ)

__global__ __launch_bounds__(512) void sdtw_fwd(
    const float* __restrict__ outp, const float* __restrict__ targ,
    float* __restrict__ Rws, float* __restrict__ vals, int kbase) {
    const int i = threadIdx.x;                    // row index
    const int k = kbase + blockIdx.x;             // batch sample
    float* __restrict__ Rslab = Rws + (size_t)blockIdx.x * SLAB;

    __shared__ float o_sh[N_SEQ];
    __shared__ float dbuf[3][N_SEQ];              // rotating anti-diagonals of R

    o_sh[i] = outp[(size_t)k * N_SEQ + i];
    const float ti = targ[(size_t)k * N_SEQ + i];
    dbuf[0][i] = BIG; dbuf[1][i] = BIG; dbuf[2][i] = BIG;
    __syncthreads();

    for (int d = 0; d < NDIAG; ++d) {
        const int j = d - i;                      // column of cell (i,j) on diagonal d
        float* __restrict__ r1buf = dbuf[(d + 2) % 3];  // diag d-1
        float* __restrict__ r2buf = dbuf[(d + 1) % 3];  // diag d-2
        float* __restrict__ r0buf = dbuf[d % 3];        // diag d (write)
        float r0 = BIG;
        if (j >= 0 && j < N_SEQ) {
            float a = (i >= 1) ? r1buf[i - 1] : BIG;                       // R[i-1, j]
            float b = (i >= 1) ? r2buf[i - 1] : ((d == 0) ? 0.0f : BIG);   // R[i-1, j-1] (virtual 0 at start)
            float c = r1buf[i];                                            // R[i, j-1]
            float m = fminf(a, fminf(b, c));
            float s = __expf((m - a) * INVG) + __expf((m - b) * INVG) + __expf((m - c) * INVG);
            float smin = m - GAMMA * __logf(s);
            float dv = ti - o_sh[j];
            r0 = dv * dv + smin;
            if (d == NDIAG - 1 && i == N_SEQ - 1) vals[k] = r0;  // R[N-1, N-1]
        }
        r0buf[i] = r0;
        Rslab[(size_t)d * N_SEQ + i] = r0;        // coalesced diagonal store
        __syncthreads();
    }
}

__global__ __launch_bounds__(512) void sdtw_bwd(
    const float* __restrict__ outp, const float* __restrict__ targ,
    const float* __restrict__ Rws, float* __restrict__ svals, int kbase) {
    const int i = threadIdx.x;
    const int k = kbase + blockIdx.x;
    const float* __restrict__ Rslab = Rws + (size_t)blockIdx.x * SLAB;

    __shared__ float o_sh[N_SEQ];
    __shared__ float t_sh[N_SEQ];
    __shared__ float Rb[3][N_SEQ];
    __shared__ float Eb[3][N_SEQ];
    __shared__ float red[8];

    o_sh[i] = outp[(size_t)k * N_SEQ + i];
    const float ti = targ[(size_t)k * N_SEQ + i];
    t_sh[i] = ti;
    for (int q = 0; q < 3; ++q) { Rb[q][i] = BIG; Eb[q][i] = 0.0f; }
    __syncthreads();

    float Rcur = Rslab[(size_t)(NDIAG - 1) * N_SEQ + i];  // diag 2N-2
    float acc = 0.0f;

    for (int d = NDIAG - 1; d >= 0; --d) {
        // prefetch next (earlier) diagonal of R; latency hides under compute + barrier
        float Rnext = 0.0f;
        if (d > 0) Rnext = Rslab[(size_t)(d - 1) * N_SEQ + i];

        const int j = d - i;
        float* __restrict__ Rb1 = Rb[(d + 1) % 3];  // diag d+1
        float* __restrict__ Rb2 = Rb[(d + 2) % 3];  // diag d+2
        float* __restrict__ Rb0 = Rb[d % 3];
        float* __restrict__ Eb1 = Eb[(d + 1) % 3];
        float* __restrict__ Eb2 = Eb[(d + 2) % 3];
        float* __restrict__ Eb0 = Eb[d % 3];

        float Ecur = 0.0f;
        if (j >= 0 && j < N_SEQ) {
            if (d == NDIAG - 1) {
                Ecur = 1.0f;                          // E[N-1,N-1] = 1
            } else {
                const float rij = Rcur;
                float e = 0.0f;
                if (i + 1 < N_SEQ) {
                    float tn = t_sh[i + 1];
                    float dv = tn - o_sh[j];          // child (i+1, j) on diag d+1
                    e += Eb1[i + 1] * __expf((Rb1[i + 1] - dv * dv - rij) * INVG);
                    if (j + 1 < N_SEQ) {
                        float dv2 = tn - o_sh[j + 1]; // child (i+1, j+1) on diag d+2
                        e += Eb2[i + 1] * __expf((Rb2[i + 1] - dv2 * dv2 - rij) * INVG);
                    }
                }
                if (j + 1 < N_SEQ) {
                    float dv3 = ti - o_sh[j + 1];     // child (i, j+1) on diag d+1
                    e += Eb1[i] * __expf((Rb1[i] - dv3 * dv3 - rij) * INVG);
                }
                Ecur = e;
            }
            float diff = (float)(i - j);
            acc += Ecur * diff * diff;                // omega[i,j] = (i-j)^2
        }
        Rb0[i] = Rcur;
        Eb0[i] = Ecur;
        __syncthreads();
        Rcur = Rnext;
    }

    // block reduction of acc (512 threads = 8 waves)
    for (int off = 32; off; off >>= 1) acc += __shfl_down(acc, off);
    if ((i & 63) == 0) red[i >> 6] = acc;
    __syncthreads();
    if (i == 0) {
        float s = 0.0f;
        for (int w = 0; w < 8; ++w) s += red[w];
        svals[k] = s;
    }
}

__global__ void finalize_kernel(const float* __restrict__ vals,
                                const float* __restrict__ svals,
                                float* __restrict__ out, int B) {
    int t = threadIdx.x;
    float v = 0.0f, s = 0.0f;
    for (int k = t; k < B; k += 64) { v += vals[k]; s += svals[k]; }
    for (int off = 32; off; off >>= 1) { v += __shfl_down(v, off); s += __shfl_down(s, off); }
    if (t == 0) {
        float loss_shape = v / (float)B;
        float loss_temporal = (s / (float)B) / ((float)N_SEQ * (float)N_SEQ);
        out[0] = ALPHA * loss_shape + (1.0f - ALPHA) * loss_temporal;
    }
}

extern "C" void kernel_launch(void* const* d_in, const int* in_sizes, int n_in,
                              void* d_out, int out_size, void* d_ws, size_t ws_size,
                              hipStream_t stream) {
    const float* outputs = (const float*)d_in[0];
    const float* targets = (const float*)d_in[1];
    const int B = in_sizes[0] / N_SEQ;  // 64

    // ws layout: [0,512B) vals, [512B,1024B) svals, [1024B, ...) R slabs
    float* vals  = (float*)d_ws;
    float* svals = vals + 128;
    float* Rws   = vals + 256;

    size_t slab_bytes = SLAB * sizeof(float);
    size_t avail = (ws_size > 1024) ? (ws_size - 1024) / slab_bytes : 0;
    int G = (int)((avail < (size_t)B) ? avail : (size_t)B);
    if (G < 1) G = 1;  // last-resort; ws_size is expected to be >= 1 slab

    for (int kb = 0; kb < B; kb += G) {
        int g = B - kb < G ? B - kb : G;
        sdtw_fwd<<<dim3(g), dim3(N_SEQ), 0, stream>>>(outputs, targets, Rws, vals, kb);
        sdtw_bwd<<<dim3(g), dim3(N_SEQ), 0, stream>>>(outputs, targets, Rws, svals, kb);
    }
    finalize_kernel<<<dim3(1), dim3(64), 0, stream>>>(vals, svals, (float*)d_out, B);
}